// Round 1
// baseline (1237.474 us; speedup 1.0000x reference)
//
#include <hip/hip_runtime.h>
#include <math.h>

// Problem constants
#define BB 64
#define LL 24
#define DD 512
#define HH 512
#define GG 2560   // 5*H
#define KS 8      // K-split for per-step a/b GEMM

__device__ __forceinline__ float sigm(float x) { return 1.0f / (1.0f + __expf(-x)); }

// ---------------------------------------------------------------------------
// init: seq[b][j] = j ; kpos/msel zeroed defensively
// ---------------------------------------------------------------------------
__global__ void init_k(int* __restrict__ seq, int* __restrict__ kpos, int* __restrict__ msel) {
    int tid = threadIdx.x;
    for (int idx = tid; idx < BB * LL; idx += 256) seq[idx] = idx % LL;
    if (tid < BB) { kpos[tid] = 0; msel[tid] = 0; }
}

// ---------------------------------------------------------------------------
// Generic fp32 tiled GEMM, C[m][n] = sum_k A[m][k] * W[n][k] (+bias)
// MODE 0 = WORD  : A=inp rows (1536x512), W=word_W (1024x512), out-> h|c
// MODE 1 = AB0   : A=h rows (1536x512), W=comp_W halves (5120 "rows" x512), out-> a|b caches
// MODE 2 = ABSTEP: A=h[b][msel[b]] rows (64x512), k-split partials out
// ---------------------------------------------------------------------------
template <int MODE, int MT, int NT, int KT, int KRANGE>
__global__ __launch_bounds__((MT / 8) * (NT / 8))
void gemm_k(const float* __restrict__ A, const float* __restrict__ Wt,
            const float* __restrict__ bias, float* __restrict__ O0,
            float* __restrict__ O1, const int* __restrict__ msel) {
    constexpr int TTH = (MT / 8) * (NT / 8);
    const int tid = threadIdx.x;
    const int nb = blockIdx.x;
    const int mb = blockIdx.y;
    const int kb = blockIdx.z;

    __shared__ float As[KT][MT + 1];
    __shared__ float Bs[KT][NT + 1];

    float acc[8][8];
#pragma unroll
    for (int y = 0; y < 8; ++y)
#pragma unroll
        for (int x = 0; x < 8; ++x) acc[y][x] = 0.f;

    const int tn = tid % (NT / 8);
    const int tm = tid / (NT / 8);
    const int n0 = nb * NT;
    const int m0 = mb * MT;
    const int k00 = (MODE == 2) ? kb * KRANGE : 0;

    for (int kt = 0; kt < KRANGE; kt += KT) {
        const int kbase = k00 + kt;
        // A tile: MT x KT
        {
            constexpr int NF4 = MT * KT / 4;
#pragma unroll
            for (int idx = tid; idx < NF4; idx += TTH) {
                int r = idx / (KT / 4);
                int c4 = idx % (KT / 4);
                const float* arow;
                if constexpr (MODE == 2) {
                    int b = m0 + r;
                    arow = A + (size_t)(b * LL + msel[b]) * DD;
                } else {
                    arow = A + (size_t)(m0 + r) * DD;
                }
                float4 v = *(const float4*)(arow + kbase + c4 * 4);
                As[c4 * 4 + 0][r] = v.x;
                As[c4 * 4 + 1][r] = v.y;
                As[c4 * 4 + 2][r] = v.z;
                As[c4 * 4 + 3][r] = v.w;
            }
        }
        // B tile: NT x KT
        {
            constexpr int NF4 = NT * KT / 4;
#pragma unroll
            for (int idx = tid; idx < NF4; idx += TTH) {
                int r = idx / (KT / 4);
                int c4 = idx % (KT / 4);
                int n = n0 + r;
                const float* wrow;
                if constexpr (MODE == 0) {
                    wrow = Wt + (size_t)n * DD;
                } else {
                    wrow = (n < GG) ? (Wt + (size_t)n * (2 * DD))
                                    : (Wt + (size_t)(n - GG) * (2 * DD) + DD);
                }
                float4 v = *(const float4*)(wrow + kbase + c4 * 4);
                Bs[c4 * 4 + 0][r] = v.x;
                Bs[c4 * 4 + 1][r] = v.y;
                Bs[c4 * 4 + 2][r] = v.z;
                Bs[c4 * 4 + 3][r] = v.w;
            }
        }
        __syncthreads();
#pragma unroll 4
        for (int k = 0; k < KT; ++k) {
            float av[8], bv[8];
#pragma unroll
            for (int y = 0; y < 8; ++y) av[y] = As[k][tm * 8 + y];
#pragma unroll
            for (int x = 0; x < 8; ++x) bv[x] = Bs[k][tn * 8 + x];
#pragma unroll
            for (int y = 0; y < 8; ++y)
#pragma unroll
                for (int x = 0; x < 8; ++x) acc[y][x] += av[y] * bv[x];
        }
        __syncthreads();
    }

    // epilogue (n-block fully inside one output half for WORD/AB0)
#pragma unroll
    for (int y = 0; y < 8; ++y) {
        const int m = m0 + tm * 8 + y;
        float* dst;
        if constexpr (MODE == 0) {
            dst = (n0 < DD) ? (O0 + (size_t)m * DD + n0) : (O1 + (size_t)m * DD + (n0 - DD));
        } else if constexpr (MODE == 1) {
            dst = (n0 < GG) ? (O0 + (size_t)m * GG + n0) : (O1 + (size_t)m * GG + (n0 - GG));
        } else {
            dst = O0 + (size_t)(m * KS + kb) * (2 * GG) + n0;
        }
#pragma unroll
        for (int xh = 0; xh < 2; ++xh) {
            float4 v;
            v.x = acc[y][xh * 4 + 0];
            v.y = acc[y][xh * 4 + 1];
            v.z = acc[y][xh * 4 + 2];
            v.w = acc[y][xh * 4 + 3];
            if constexpr (MODE == 0) {
                int nl = n0 + tn * 8 + xh * 4;
                v.x += bias[nl + 0];
                v.y += bias[nl + 1];
                v.z += bias[nl + 2];
                v.w += bias[nl + 3];
            }
            *(float4*)(dst + tn * 8 + xh * 4) = v;
        }
    }
}

// ---------------------------------------------------------------------------
// candidate score: full-block computation of q . new_h for pair (sl, sr)
// ---------------------------------------------------------------------------
__device__ float score_cand(const float* __restrict__ ar, const float* __restrict__ br,
                            const float* __restrict__ cb, const float* __restrict__ cl,
                            const float* __restrict__ cr, const float* __restrict__ q,
                            float* red, int tid) {
    float part = 0.f;
#pragma unroll
    for (int d = tid; d < DD; d += 256) {
        float gi = ar[d] + br[d] + cb[d];
        float gfl = ar[DD + d] + br[DD + d] + cb[DD + d];
        float gfr = ar[2 * DD + d] + br[2 * DD + d] + cb[2 * DD + d];
        float gu = ar[3 * DD + d] + br[3 * DD + d] + cb[3 * DD + d];
        float go = ar[4 * DD + d] + br[4 * DD + d] + cb[4 * DD + d];
        float nc = cl[d] * sigm(gfl + 1.f) + cr[d] * sigm(gfr + 1.f) + tanhf(gu) * sigm(gi);
        float nh = sigm(go) * tanhf(nc);
        part += nh * q[d];
    }
    red[tid] = part;
    __syncthreads();
#pragma unroll
    for (int s = 128; s > 0; s >>= 1) {
        if (tid < s) red[tid] += red[tid + s];
        __syncthreads();
    }
    float r = red[0];
    __syncthreads();
    return r;
}

// ---------------------------------------------------------------------------
// step-0 scores for all candidates (identity seq)
// ---------------------------------------------------------------------------
__global__ __launch_bounds__(256) void scoreall_k(const float* __restrict__ acache,
                                                  const float* __restrict__ bcache,
                                                  const float* __restrict__ cbuf,
                                                  const float* __restrict__ compb,
                                                  const float* __restrict__ q,
                                                  float* __restrict__ scores) {
    __shared__ float red[256];
    const int p = blockIdx.x;  // 0..22
    const int b = blockIdx.y;
    const float* ar = acache + (size_t)(b * LL + p) * GG;
    const float* br = bcache + (size_t)(b * LL + p + 1) * GG;
    const float* cl = cbuf + (size_t)(b * LL + p) * DD;
    const float* cr = cbuf + (size_t)(b * LL + p + 1) * DD;
    float s = score_cand(ar, br, compb, cl, cr, q, red, threadIdx.x);
    if (threadIdx.x == 0) scores[b * (LL - 1) + p] = s;
}

// ---------------------------------------------------------------------------
// per-step: reduce partials -> refresh 2 scores -> argmax -> merge -> shift
// one block per batch
// ---------------------------------------------------------------------------
__global__ __launch_bounds__(256) void selmerge_k(
    int step, const int* __restrict__ length, float* __restrict__ hbuf, float* __restrict__ cbuf,
    float* __restrict__ acache, float* __restrict__ bcache, const float* __restrict__ part,
    float* __restrict__ scores, int* __restrict__ seq, int* __restrict__ kpos,
    int* __restrict__ msel, const float* __restrict__ compb, const float* __restrict__ q,
    float* __restrict__ out) {
    __shared__ float s_lds[32];
    __shared__ int seq_lds[32];
    __shared__ float red[256];
    __shared__ int k_sh;

    const int b = blockIdx.x;
    const int tid = threadIdx.x;
    const int i = step;
    const int len_items = LL - i;
    const int ncand = len_items - 1;
    const int lenb = length[b];

    if (tid < ncand) s_lds[tid] = scores[b * (LL - 1) + tid];
    if (tid < len_items) seq_lds[tid] = seq[b * LL + tid];
    __syncthreads();

    if (i > 0 && i < lenb) {  // batch was active at step i-1
        // reduce k-split partials of the merged item's a/b rows
        const int sm = msel[b];
        const int row = b * LL + sm;
        for (int n = tid; n < 2 * GG; n += 256) {
            float s = 0.f;
#pragma unroll
            for (int kk = 0; kk < KS; ++kk) s += part[(size_t)(b * KS + kk) * (2 * GG) + n];
            if (n < GG) acache[(size_t)row * GG + n] = s;
            else bcache[(size_t)row * GG + (n - GG)] = s;
        }
        __syncthreads();
        const int kp = kpos[b];
        for (int p = kp - 1; p <= kp; ++p) {
            if (p < 0 || p > ncand - 1) continue;
            const int sl = seq_lds[p], sr = seq_lds[p + 1];
            float sc = score_cand(acache + (size_t)(b * LL + sl) * GG,
                                  bcache + (size_t)(b * LL + sr) * GG, compb,
                                  cbuf + (size_t)(b * LL + sl) * DD,
                                  cbuf + (size_t)(b * LL + sr) * DD, q, red, tid);
            if (tid == 0) {
                s_lds[p] = sc;
                scores[b * (LL - 1) + p] = sc;
            }
            __syncthreads();
        }
    }

    const bool done = (i + 1) < lenb;
    if (done) {
        const int vmax = lenb - i - 2;  // max valid candidate index (>=0)
        if (tid == 0) {
            int k = 0;
            float best = s_lds[0];
            for (int p = 1; p <= vmax; ++p)
                if (s_lds[p] > best) { best = s_lds[p]; k = p; }  // first-max tiebreak
            k_sh = k;
        }
        __syncthreads();
        const int k = k_sh;
        const int sl = seq_lds[k], sr = seq_lds[k + 1];
        // recompute winner gates; write merged h,c into slot sl
        {
            const float* ar = acache + (size_t)(b * LL + sl) * GG;
            const float* br = bcache + (size_t)(b * LL + sr) * GG;
            const float* cl = cbuf + (size_t)(b * LL + sl) * DD;
            const float* cr = cbuf + (size_t)(b * LL + sr) * DD;
            float* hw = hbuf + (size_t)(b * LL + sl) * DD;
            float* cw = cbuf + (size_t)(b * LL + sl) * DD;
            for (int d = tid; d < DD; d += 256) {
                float gi = ar[d] + br[d] + compb[d];
                float gfl = ar[DD + d] + br[DD + d] + compb[DD + d];
                float gfr = ar[2 * DD + d] + br[2 * DD + d] + compb[2 * DD + d];
                float gu = ar[3 * DD + d] + br[3 * DD + d] + compb[3 * DD + d];
                float go = ar[4 * DD + d] + br[4 * DD + d] + compb[4 * DD + d];
                float nc = cl[d] * sigm(gfl + 1.f) + cr[d] * sigm(gfr + 1.f) + tanhf(gu) * sigm(gi);
                float nh = sigm(go) * tanhf(nc);
                hw[d] = nh;
                cw[d] = nc;
            }
        }
        // shifts (from LDS copies; no hazards)
        if (tid >= k + 1 && tid <= ncand - 2) scores[b * (LL - 1) + tid] = s_lds[tid + 1];
        if (tid >= k + 1 && tid <= len_items - 2) seq[b * LL + tid] = seq_lds[tid + 1];
        if (tid == 0) { kpos[b] = k; msel[b] = sl; }
    }

    if (i == LL - 2) {  // last step: emit h[:,0,:]
        __syncthreads();
        const int s0 = seq_lds[0];  // position 0 never shifts
        for (int d = tid; d < DD; d += 256) out[b * DD + d] = hbuf[(size_t)(b * LL + s0) * DD + d];
    }
}

// ---------------------------------------------------------------------------
extern "C" void kernel_launch(void* const* d_in, const int* in_sizes, int n_in, void* d_out,
                              int out_size, void* d_ws, size_t ws_size, hipStream_t stream) {
    const float* inp = (const float*)d_in[0];
    const int* length = (const int*)d_in[1];
    const float* word_W = (const float*)d_in[2];
    const float* word_b = (const float*)d_in[3];
    const float* comp_W = (const float*)d_in[4];
    const float* comp_b = (const float*)d_in[5];
    const float* comp_q = (const float*)d_in[6];
    float* out = (float*)d_out;

    float* ws = (float*)d_ws;
    size_t off = 0;
    float* hbuf = ws + off;   off += (size_t)BB * LL * DD;        // 786432
    float* cbuf = ws + off;   off += (size_t)BB * LL * DD;        // 786432
    float* acache = ws + off; off += (size_t)BB * LL * GG;        // 3932160
    float* bcache = ws + off; off += (size_t)BB * LL * GG;        // 3932160
    float* part = ws + off;   off += (size_t)BB * KS * 2 * GG;    // 2621440
    float* scores = ws + off; off += 2048;
    int* seq = (int*)(ws + off);  off += BB * LL;
    int* kpos = (int*)(ws + off); off += 64;
    int* msel = (int*)(ws + off); off += 64;
    (void)ws_size; (void)in_sizes; (void)n_in; (void)out_size;

    init_k<<<1, 256, 0, stream>>>(seq, kpos, msel);

    // word projection: h,c = split(inp @ word_W.T + word_b)
    gemm_k<0, 64, 128, 32, 512><<<dim3(8, 24, 1), 128, 0, stream>>>(
        inp, word_W, word_b, hbuf, cbuf, nullptr);

    // a/b caches for all 1536 items: a = W_L @ h, b = W_R @ h
    gemm_k<1, 128, 128, 16, 512><<<dim3(40, 12, 1), 256, 0, stream>>>(
        hbuf, comp_W, nullptr, acache, bcache, nullptr);

    // step-0 scores for all 23 candidates per batch
    scoreall_k<<<dim3(23, 64, 1), 256, 0, stream>>>(acache, bcache, cbuf, comp_b, comp_q, scores);

    for (int i = 0; i < LL - 1; ++i) {
        selmerge_k<<<64, 256, 0, stream>>>(i, length, hbuf, cbuf, acache, bcache, part, scores,
                                           seq, kpos, msel, comp_b, comp_q, out);
        if (i < LL - 2) {
            // a/b of the freshly merged item (M=64), k-split into 8 partials
            gemm_k<2, 64, 128, 32, 64><<<dim3(40, 1, 8), 128, 0, stream>>>(
                hbuf, comp_W, nullptr, part, nullptr, msel);
        }
    }
}